// Round 1
// baseline (1352.725 us; speedup 1.0000x reference)
//
#include <hip/hip_runtime.h>

// HybridMambaBlock pipeline:
//  1) cvt: W_in/W_res/W_out f32 -> bf16 (W_in padded to OPAD rows, zero fill)
//  2) ln: LayerNorm(x) -> xn(bf16); also x -> bf16 for the residual GEMM
//  3) gemm_bt<bf16 out>: p = xn @ W_in^T   (2048 x 52352, the big one)
//  4) gemm_bt<f32 out>:  res = x @ W_res^T
//  5) conv: depthwise causal conv K=4 on u slice of p -> u_conv (f32)
//  6) dt: dt = clip(softplus(dth @ W_dt^T + bias), 1e-4, 1)
//  7) scan: h_t = exp(dt*A)*h + dt*u*B; y_t = C.h + u*Dskip  (prefetch depth 8)
//  8) gate: g = rmsnorm(y*silu(z))*norm_w + res -> bf16
//  9) gemm_bt<f32 out>: out = g @ W_out^T

typedef unsigned short u16;
typedef __bf16 bf16x8 __attribute__((ext_vector_type(8)));
typedef float f32x4 __attribute__((ext_vector_type(4)));

#define OPAD 52352   // 409*128 >= 52272
#define OTOT 52272
#define DI   1536
#define DM   768
#define Z0   0
#define U0   1536
#define DTH0 3072
#define B0   3120
#define C0   27696

__device__ static inline u16 f2bf(float f) {
    unsigned u = __float_as_uint(f);
    u += 0x7fffu + ((u >> 16) & 1u);
    return (u16)(u >> 16);
}
__device__ static inline float bf2f(u16 s) {
    return __uint_as_float(((unsigned)s) << 16);
}

__device__ static inline void gload16(const void* g, void* l) {
    __builtin_amdgcn_global_load_lds(
        (const __attribute__((address_space(1))) unsigned int*)g,
        (__attribute__((address_space(3))) unsigned int*)l, 16, 0, 0);
}

// ---------------- f32 -> bf16 convert (with zero pad to n_tot) ----------------
__global__ void cvt_kernel(const float* __restrict__ src, u16* __restrict__ dst,
                           long n_src, long n_tot) {
    long i4 = ((long)blockIdx.x * 256 + threadIdx.x) * 4;
    if (i4 >= n_tot) return;
    ushort4 o;
    if (i4 < n_src) {  // n_src is a multiple of 4 for all callers
        float4 v = *(const float4*)(src + i4);
        o.x = f2bf(v.x); o.y = f2bf(v.y); o.z = f2bf(v.z); o.w = f2bf(v.w);
    } else {
        o.x = o.y = o.z = o.w = 0;
    }
    *(ushort4*)(dst + i4) = o;
}

// ---------------- block reduce (sum of two values across 256 threads) --------
__device__ static inline void block_reduce2(float& a, float& b) {
    #pragma unroll
    for (int o = 32; o > 0; o >>= 1) {
        a += __shfl_down(a, o);
        b += __shfl_down(b, o);
    }
    __shared__ float sa[4], sb[4];
    int lane = threadIdx.x & 63, w = threadIdx.x >> 6;
    if (lane == 0) { sa[w] = a; sb[w] = b; }
    __syncthreads();
    a = sa[0] + sa[1] + sa[2] + sa[3];
    b = sb[0] + sb[1] + sb[2] + sb[3];
}

// ---------------- LayerNorm -> xn bf16, plus raw x -> bf16 -------------------
__global__ void __launch_bounds__(256) ln_kernel(const float* __restrict__ x,
        const float* __restrict__ w, const float* __restrict__ b,
        u16* __restrict__ xnbf, u16* __restrict__ xbf) {
    int m = blockIdx.x, tid = threadIdx.x;
    const float* xr = x + (size_t)m * DM;
    float v[3];
    v[0] = xr[tid]; v[1] = xr[tid + 256]; v[2] = xr[tid + 512];
    float s = v[0] + v[1] + v[2];
    float ss = v[0]*v[0] + v[1]*v[1] + v[2]*v[2];
    block_reduce2(s, ss);
    float mu = s * (1.f / DM);
    float var = ss * (1.f / DM) - mu * mu;
    float inv = rsqrtf(var + 1e-5f);
    #pragma unroll
    for (int i = 0; i < 3; ++i) {
        int d = tid + i * 256;
        float xn = (v[i] - mu) * inv * w[d] + b[d];
        xnbf[(size_t)m * DM + d] = f2bf(xn);
        xbf[(size_t)m * DM + d] = f2bf(v[i]);
    }
}

// ---------------- bf16 MFMA GEMM: C[M,N] = A[M,K] * B[N,K]^T -----------------
// 128x128 tile, BK=64, 256 threads (4 waves, each 64x64 via 4x4 of 16x16x32).
template <int OUT_BF16>
__global__ void __launch_bounds__(256) gemm_bt(const u16* __restrict__ A,
        const u16* __restrict__ B, void* __restrict__ C, int K, int ldc) {
    __shared__ u16 smem[2 * 128 * 64];
    u16* As = smem;
    u16* Bs = smem + 128 * 64;
    int tid = threadIdx.x;
    int m0 = blockIdx.y * 128, n0 = blockIdx.x * 128;
    int lane = tid & 63, wave = tid >> 6;
    int wm = wave >> 1, wn = wave & 1;
    int l15 = lane & 15, l4 = lane >> 4;
    f32x4 acc[4][4] = {};
    const u16* Ag = A + (size_t)m0 * K;
    const u16* Bg = B + (size_t)n0 * K;
    int crow = tid >> 3;            // 0..31
    int ccol = (tid & 7) * 8;       // element offset within 64-wide k tile
    int ldsoff = (tid & 192) * 16;  // wave*1024 bytes

    for (int k0 = 0; k0 < K; k0 += 64) {
        __syncthreads();
        #pragma unroll
        for (int it = 0; it < 4; ++it) {
            gload16(Ag + (size_t)(it * 32 + crow) * K + k0 + ccol,
                    (char*)As + it * 4096 + ldsoff);
            gload16(Bg + (size_t)(it * 32 + crow) * K + k0 + ccol,
                    (char*)Bs + it * 4096 + ldsoff);
        }
        __syncthreads();
        const u16* Ab = As + (wm * 64 + l15) * 64 + l4 * 8;
        const u16* Bb = Bs + (wn * 64 + l15) * 64 + l4 * 8;
        #pragma unroll
        for (int kk = 0; kk < 64; kk += 32) {
            bf16x8 af[4], bfr[4];
            #pragma unroll
            for (int i = 0; i < 4; ++i) af[i] = *(const bf16x8*)(Ab + i * 16 * 64 + kk);
            #pragma unroll
            for (int j = 0; j < 4; ++j) bfr[j] = *(const bf16x8*)(Bb + j * 16 * 64 + kk);
            #pragma unroll
            for (int i = 0; i < 4; ++i)
                #pragma unroll
                for (int j = 0; j < 4; ++j)
                    acc[i][j] = __builtin_amdgcn_mfma_f32_16x16x32_bf16(
                        af[i], bfr[j], acc[i][j], 0, 0, 0);
        }
    }
    #pragma unroll
    for (int i = 0; i < 4; ++i) {
        int row = m0 + wm * 64 + i * 16 + l4 * 4;
        #pragma unroll
        for (int j = 0; j < 4; ++j) {
            int col = n0 + wn * 64 + j * 16 + l15;
            #pragma unroll
            for (int r = 0; r < 4; ++r) {
                size_t off = (size_t)(row + r) * ldc + col;
                if (OUT_BF16) ((u16*)C)[off] = f2bf(acc[i][j][r]);
                else          ((float*)C)[off] = acc[i][j][r];
            }
        }
    }
}

// ---------------- depthwise causal conv (K=4) --------------------------------
__global__ void __launch_bounds__(256) conv_kernel(const u16* __restrict__ p,
        const float* __restrict__ cw, const float* __restrict__ cb,
        float* __restrict__ u) {
    int d = blockIdx.x * 256 + threadIdx.x;  // 0..1535
    int m = blockIdx.y;                      // 0..2047
    int l = m & 1023;
    int bm = m - l;                          // b*1024
    float acc = cb[d];
    #pragma unroll
    for (int j = 0; j < 4; ++j) {
        int ls = l - 3 + j;
        if (ls >= 0)
            acc += cw[d * 4 + j] * bf2f(p[(size_t)(bm + ls) * OPAD + U0 + d]);
    }
    u[(size_t)m * DI + d] = acc;
}

// ---------------- dt = clip(softplus(dth @ W_dt^T + bias)) -------------------
__global__ void __launch_bounds__(256) dt_kernel(const u16* __restrict__ p,
        const float* __restrict__ Wdt, const float* __restrict__ dt_bias,
        float* __restrict__ dt) {
    int m0 = blockIdx.x * 16, tid = threadIdx.x;
    __shared__ float dth_s[16 * 48];
    for (int i = tid; i < 16 * 48; i += 256)
        dth_s[i] = bf2f(p[(size_t)(m0 + i / 48) * OPAD + DTH0 + (i % 48)]);
    __syncthreads();
    #pragma unroll
    for (int ii = 0; ii < 6; ++ii) {
        int d = ii * 256 + tid;
        float base = dt_bias[d];
        float acc[16];
        #pragma unroll
        for (int mm = 0; mm < 16; ++mm) acc[mm] = base;
        for (int r = 0; r < 48; ++r) {
            float wv = Wdt[d * 48 + r];
            #pragma unroll
            for (int mm = 0; mm < 16; ++mm)
                acc[mm] = fmaf(wv, dth_s[mm * 48 + r], acc[mm]);
        }
        #pragma unroll
        for (int mm = 0; mm < 16; ++mm) {
            float xv = acc[mm];
            float sp = xv > 20.f ? xv : log1pf(__expf(xv));
            sp = fminf(fmaxf(sp, 1e-4f), 1.0f);
            dt[(size_t)(m0 + mm) * DI + d] = sp;
        }
    }
}

// ---------------- selective scan (16 d x 16 n per block, prefetch 8) ---------
__global__ void __launch_bounds__(256) scan_kernel(const u16* __restrict__ p,
        const float* __restrict__ dt, const float* __restrict__ u,
        const float* __restrict__ A_log, const float* __restrict__ Dskip,
        float* __restrict__ y) {
    int tid = threadIdx.x;
    int n = tid & 15, dl = tid >> 4;
    int d = blockIdx.x * 16 + dl;
    int b = blockIdx.y;
    float A_dn = -__expf(A_log[d * 16 + n]);
    float Dsk = Dskip[d];
    const u16* Bb = p + (size_t)b * 1024 * OPAD + B0 + d * 16 + n;
    const u16* Cb = p + (size_t)b * 1024 * OPAD + C0 + d * 16 + n;
    const float* dtb = dt + (size_t)b * 1024 * DI + d;
    const float* ub  = u  + (size_t)b * 1024 * DI + d;
    float* yb        = y  + (size_t)b * 1024 * DI + d;
    u16 Bp[8], Cp[8];
    float dtp[8], up[8];
    #pragma unroll
    for (int i = 0; i < 8; ++i) {
        Bp[i] = Bb[(size_t)i * OPAD];
        Cp[i] = Cb[(size_t)i * OPAD];
        dtp[i] = dtb[(size_t)i * DI];
        up[i]  = ub[(size_t)i * DI];
    }
    float h = 0.f;
    for (int t0 = 0; t0 < 1024; t0 += 8) {
        #pragma unroll
        for (int s = 0; s < 8; ++s) {
            int t = t0 + s;
            float dtv = dtp[s], uv = up[s];
            float Bv = bf2f(Bp[s]), Cv = bf2f(Cp[s]);
            int tn = t + 8;
            if (tn < 1024) {
                Bp[s] = Bb[(size_t)tn * OPAD];
                Cp[s] = Cb[(size_t)tn * OPAD];
                dtp[s] = dtb[(size_t)tn * DI];
                up[s]  = ub[(size_t)tn * DI];
            }
            float dA = __expf(dtv * A_dn);
            h = fmaf(dA, h, dtv * uv * Bv);
            float part = Cv * h;
            part += __shfl_xor(part, 1);
            part += __shfl_xor(part, 2);
            part += __shfl_xor(part, 4);
            part += __shfl_xor(part, 8);
            if (n == 0) yb[(size_t)t * DI] = part + uv * Dsk;
        }
    }
}

// ---------------- gating + RMSNorm + residual -> g (bf16) --------------------
__global__ void __launch_bounds__(256) gate_kernel(const u16* __restrict__ p,
        const float* __restrict__ y, const float* __restrict__ res,
        const float* __restrict__ norm_w, u16* __restrict__ g) {
    int m = blockIdx.x, tid = threadIdx.x;
    const u16* pz = p + (size_t)m * OPAD + Z0;
    const float* yr = y + (size_t)m * DI;
    float gp[6];
    float ss = 0.f, dummy = 0.f;
    #pragma unroll
    for (int i = 0; i < 6; ++i) {
        int d = i * 256 + tid;
        float z = bf2f(pz[d]);
        float gv = yr[d] * z / (1.f + __expf(-z));
        gp[i] = gv;
        ss += gv * gv;
    }
    block_reduce2(ss, dummy);
    float scale = rsqrtf(ss * (1.f / DI) + 1e-6f);
    #pragma unroll
    for (int i = 0; i < 6; ++i) {
        int d = i * 256 + tid;
        float val = gp[i] * scale * norm_w[d] + res[(size_t)m * DI + d];
        g[(size_t)m * DI + d] = f2bf(val);
    }
}

// ---------------- host ----------------
extern "C" void kernel_launch(void* const* d_in, const int* in_sizes, int n_in,
                              void* d_out, int out_size, void* d_ws, size_t ws_size,
                              hipStream_t stream) {
    const float* x       = (const float*)d_in[0];
    const float* ln_w    = (const float*)d_in[1];
    const float* ln_b    = (const float*)d_in[2];
    const float* W_in    = (const float*)d_in[3];
    const float* W_dt    = (const float*)d_in[4];
    const float* conv_w  = (const float*)d_in[5];
    const float* conv_b  = (const float*)d_in[6];
    const float* A_log   = (const float*)d_in[7];
    const float* Dskip   = (const float*)d_in[8];
    const float* dt_bias = (const float*)d_in[9];
    const float* norm_w  = (const float*)d_in[10];
    const float* W_res   = (const float*)d_in[11];
    const float* W_out   = (const float*)d_in[12];
    float* out = (float*)d_out;

    char* wsb = (char*)d_ws;
    u16* Wbf     = (u16*)(wsb + 0);           //  80,412,672  (OPAD*768*2)
    u16* Wresbf  = (u16*)(wsb + 80412672);    //   2,359,296
    u16* Woutbf  = (u16*)(wsb + 82771968);    //   2,359,296
    u16* xnbf    = (u16*)(wsb + 85131264);    //   3,145,728
    u16* xbf     = (u16*)(wsb + 88276992);    //   3,145,728
    u16* pbuf    = (u16*)(wsb + 91422720);    // 214,433,792  (2048*OPAD*2)
    float* ucv   = (float*)(wsb + 305856512); //  12,582,912
    float* dtv   = (float*)(wsb + 318439424); //  12,582,912
    float* ybuf  = (float*)(wsb + 331022336); //  12,582,912
    float* resb  = (float*)(wsb + 343605248); //  12,582,912
    u16* gbuf    = (u16*)(wsb + 356188160);   //   6,291,456  -> total 362,479,616

    // 1) weight converts
    cvt_kernel<<<39264, 256, 0, stream>>>(W_in, Wbf, (long)OTOT * DM, (long)OPAD * DM);
    cvt_kernel<<<1152, 256, 0, stream>>>(W_res, Wresbf, (long)DI * DM, (long)DI * DM);
    cvt_kernel<<<1152, 256, 0, stream>>>(W_out, Woutbf, (long)DM * DI, (long)DM * DI);
    // 2) layernorm
    ln_kernel<<<2048, 256, 0, stream>>>(x, ln_w, ln_b, xnbf, xbf);
    // 3) big GEMM: p = xn @ W_in^T  (bf16 out, ldc = OPAD)
    gemm_bt<1><<<dim3(409, 16), 256, 0, stream>>>(xnbf, Wbf, pbuf, DM, OPAD);
    // 4) res = x @ W_res^T (f32 out)
    gemm_bt<0><<<dim3(12, 16), 256, 0, stream>>>(xbf, Wresbf, resb, DM, DI);
    // 5) conv
    conv_kernel<<<dim3(6, 2048), 256, 0, stream>>>(pbuf, conv_w, conv_b, ucv);
    // 6) dt
    dt_kernel<<<128, 256, 0, stream>>>(pbuf, W_dt, dt_bias, dtv);
    // 7) scan
    scan_kernel<<<dim3(96, 2), 256, 0, stream>>>(pbuf, dtv, ucv, A_log, Dskip, ybuf);
    // 8) gate + rmsnorm + residual
    gate_kernel<<<2048, 256, 0, stream>>>(pbuf, ybuf, resb, norm_w, gbuf);
    // 9) out = g @ W_out^T (f32 out)
    gemm_bt<0><<<dim3(6, 16), 256, 0, stream>>>(gbuf, Woutbf, out, DI, DM);
}

// Round 2
// 897.869 us; speedup vs baseline: 1.5066x; 1.5066x over previous
//
#include <hip/hip_runtime.h>

// HybridMambaBlock pipeline:
//  1) cvt: W_in/W_res/W_out f32 -> bf16 (W_in padded to OPAD rows, zero fill)
//  2) ln: LayerNorm(x) -> xn(bf16); also x -> bf16 for the residual GEMM
//  3) gemm_bt<bf16 out>: p = xn @ W_in^T   (2048 x 52352, the big one)
//  4) gemm_bt<f32 out>:  res = x @ W_res^T
//  5) conv: depthwise causal conv K=4 on u slice of p -> u_conv (f32)
//  6) dt: dt = clip(softplus(dth @ W_dt^T + bias), 1e-4, 1)
//  7) scan: chunked-LDS selective scan (1 wave/block, 4d x 16n, T_CH=32)
//  8) gate: g = rmsnorm(y*silu(z))*norm_w + res -> bf16
//  9) gemm_bt<f32 out>: out = g @ W_out^T

typedef unsigned short u16;
typedef __bf16 bf16x8 __attribute__((ext_vector_type(8)));
typedef float f32x4 __attribute__((ext_vector_type(4)));

#define OPAD 52352   // 409*128 >= 52272
#define OTOT 52272
#define DI   1536
#define DM   768
#define Z0   0
#define U0   1536
#define DTH0 3072
#define B0   3120
#define C0   27696

__device__ static inline u16 f2bf(float f) {
    unsigned u = __float_as_uint(f);
    u += 0x7fffu + ((u >> 16) & 1u);
    return (u16)(u >> 16);
}
__device__ static inline float bf2f(u16 s) {
    return __uint_as_float(((unsigned)s) << 16);
}

__device__ static inline void gload16(const void* g, void* l) {
    __builtin_amdgcn_global_load_lds(
        (const __attribute__((address_space(1))) unsigned int*)g,
        (__attribute__((address_space(3))) unsigned int*)l, 16, 0, 0);
}

// ---------------- f32 -> bf16 convert (with zero pad to n_tot) ----------------
__global__ void cvt_kernel(const float* __restrict__ src, u16* __restrict__ dst,
                           long n_src, long n_tot) {
    long i4 = ((long)blockIdx.x * 256 + threadIdx.x) * 4;
    if (i4 >= n_tot) return;
    ushort4 o;
    if (i4 < n_src) {  // n_src is a multiple of 4 for all callers
        float4 v = *(const float4*)(src + i4);
        o.x = f2bf(v.x); o.y = f2bf(v.y); o.z = f2bf(v.z); o.w = f2bf(v.w);
    } else {
        o.x = o.y = o.z = o.w = 0;
    }
    *(ushort4*)(dst + i4) = o;
}

// ---------------- block reduce (sum of two values across 256 threads) --------
__device__ static inline void block_reduce2(float& a, float& b) {
    #pragma unroll
    for (int o = 32; o > 0; o >>= 1) {
        a += __shfl_down(a, o);
        b += __shfl_down(b, o);
    }
    __shared__ float sa[4], sb[4];
    int lane = threadIdx.x & 63, w = threadIdx.x >> 6;
    if (lane == 0) { sa[w] = a; sb[w] = b; }
    __syncthreads();
    a = sa[0] + sa[1] + sa[2] + sa[3];
    b = sb[0] + sb[1] + sb[2] + sb[3];
}

// ---------------- LayerNorm -> xn bf16, plus raw x -> bf16 -------------------
__global__ void __launch_bounds__(256) ln_kernel(const float* __restrict__ x,
        const float* __restrict__ w, const float* __restrict__ b,
        u16* __restrict__ xnbf, u16* __restrict__ xbf) {
    int m = blockIdx.x, tid = threadIdx.x;
    const float* xr = x + (size_t)m * DM;
    float v[3];
    v[0] = xr[tid]; v[1] = xr[tid + 256]; v[2] = xr[tid + 512];
    float s = v[0] + v[1] + v[2];
    float ss = v[0]*v[0] + v[1]*v[1] + v[2]*v[2];
    block_reduce2(s, ss);
    float mu = s * (1.f / DM);
    float var = ss * (1.f / DM) - mu * mu;
    float inv = rsqrtf(var + 1e-5f);
    #pragma unroll
    for (int i = 0; i < 3; ++i) {
        int d = tid + i * 256;
        float xn = (v[i] - mu) * inv * w[d] + b[d];
        xnbf[(size_t)m * DM + d] = f2bf(xn);
        xbf[(size_t)m * DM + d] = f2bf(v[i]);
    }
}

// ---------------- bf16 MFMA GEMM: C[M,N] = A[M,K] * B[N,K]^T -----------------
// 128x128 tile, BK=64, 256 threads (4 waves, each 64x64 via 4x4 of 16x16x32).
template <int OUT_BF16>
__global__ void __launch_bounds__(256) gemm_bt(const u16* __restrict__ A,
        const u16* __restrict__ B, void* __restrict__ C, int K, int ldc) {
    __shared__ u16 smem[2 * 128 * 64];
    u16* As = smem;
    u16* Bs = smem + 128 * 64;
    int tid = threadIdx.x;
    int m0 = blockIdx.y * 128, n0 = blockIdx.x * 128;
    int lane = tid & 63, wave = tid >> 6;
    int wm = wave >> 1, wn = wave & 1;
    int l15 = lane & 15, l4 = lane >> 4;
    f32x4 acc[4][4] = {};
    const u16* Ag = A + (size_t)m0 * K;
    const u16* Bg = B + (size_t)n0 * K;
    int crow = tid >> 3;            // 0..31
    int ccol = (tid & 7) * 8;       // element offset within 64-wide k tile
    int ldsoff = (tid & 192) * 16;  // wave*1024 bytes

    for (int k0 = 0; k0 < K; k0 += 64) {
        __syncthreads();
        #pragma unroll
        for (int it = 0; it < 4; ++it) {
            gload16(Ag + (size_t)(it * 32 + crow) * K + k0 + ccol,
                    (char*)As + it * 4096 + ldsoff);
            gload16(Bg + (size_t)(it * 32 + crow) * K + k0 + ccol,
                    (char*)Bs + it * 4096 + ldsoff);
        }
        __syncthreads();
        const u16* Ab = As + (wm * 64 + l15) * 64 + l4 * 8;
        const u16* Bb = Bs + (wn * 64 + l15) * 64 + l4 * 8;
        #pragma unroll
        for (int kk = 0; kk < 64; kk += 32) {
            bf16x8 af[4], bfr[4];
            #pragma unroll
            for (int i = 0; i < 4; ++i) af[i] = *(const bf16x8*)(Ab + i * 16 * 64 + kk);
            #pragma unroll
            for (int j = 0; j < 4; ++j) bfr[j] = *(const bf16x8*)(Bb + j * 16 * 64 + kk);
            #pragma unroll
            for (int i = 0; i < 4; ++i)
                #pragma unroll
                for (int j = 0; j < 4; ++j)
                    acc[i][j] = __builtin_amdgcn_mfma_f32_16x16x32_bf16(
                        af[i], bfr[j], acc[i][j], 0, 0, 0);
        }
    }
    #pragma unroll
    for (int i = 0; i < 4; ++i) {
        int row = m0 + wm * 64 + i * 16 + l4 * 4;
        #pragma unroll
        for (int j = 0; j < 4; ++j) {
            int col = n0 + wn * 64 + j * 16 + l15;
            #pragma unroll
            for (int r = 0; r < 4; ++r) {
                size_t off = (size_t)(row + r) * ldc + col;
                if (OUT_BF16) ((u16*)C)[off] = f2bf(acc[i][j][r]);
                else          ((float*)C)[off] = acc[i][j][r];
            }
        }
    }
}

// ---------------- depthwise causal conv (K=4) --------------------------------
__global__ void __launch_bounds__(256) conv_kernel(const u16* __restrict__ p,
        const float* __restrict__ cw, const float* __restrict__ cb,
        float* __restrict__ u) {
    int d = blockIdx.x * 256 + threadIdx.x;  // 0..1535
    int m = blockIdx.y;                      // 0..2047
    int l = m & 1023;
    int bm = m - l;                          // b*1024
    float acc = cb[d];
    #pragma unroll
    for (int j = 0; j < 4; ++j) {
        int ls = l - 3 + j;
        if (ls >= 0)
            acc += cw[d * 4 + j] * bf2f(p[(size_t)(bm + ls) * OPAD + U0 + d]);
    }
    u[(size_t)m * DI + d] = acc;
}

// ---------------- dt = clip(softplus(dth @ W_dt^T + bias)) -------------------
__global__ void __launch_bounds__(256) dt_kernel(const u16* __restrict__ p,
        const float* __restrict__ Wdt, const float* __restrict__ dt_bias,
        float* __restrict__ dt) {
    int m0 = blockIdx.x * 16, tid = threadIdx.x;
    __shared__ float dth_s[16 * 48];
    for (int i = tid; i < 16 * 48; i += 256)
        dth_s[i] = bf2f(p[(size_t)(m0 + i / 48) * OPAD + DTH0 + (i % 48)]);
    __syncthreads();
    #pragma unroll
    for (int ii = 0; ii < 6; ++ii) {
        int d = ii * 256 + tid;
        float base = dt_bias[d];
        float acc[16];
        #pragma unroll
        for (int mm = 0; mm < 16; ++mm) acc[mm] = base;
        for (int r = 0; r < 48; ++r) {
            float wv = Wdt[d * 48 + r];
            #pragma unroll
            for (int mm = 0; mm < 16; ++mm)
                acc[mm] = fmaf(wv, dth_s[mm * 48 + r], acc[mm]);
        }
        #pragma unroll
        for (int mm = 0; mm < 16; ++mm) {
            float xv = acc[mm];
            float sp = xv > 20.f ? xv : log1pf(__expf(xv));
            sp = fminf(fmaxf(sp, 1e-4f), 1.0f);
            dt[(size_t)(m0 + mm) * DI + d] = sp;
        }
    }
}

// ---------------- selective scan v2: chunked LDS staging ---------------------
// 1 wave per block; block owns 4 d-channels (all 16 n each). T_CH=32 timesteps
// staged per chunk: B (4KB), C (4KB) via 8x16B fully-used segments per row,
// dt/u (512B each, half-wave masked loads). Inner loop reads LDS (conflict-
// free: 2 lanes/dword broadcast), h-recurrence in a register, 4-shfl n-reduce.
__global__ void __launch_bounds__(64) scan_kernel(const u16* __restrict__ p,
        const float* __restrict__ dt, const float* __restrict__ u,
        const float* __restrict__ A_log, const float* __restrict__ Dskip,
        float* __restrict__ y) {
    __shared__ u16 Bs[32 * 64];     // [t][d*16+n]
    __shared__ u16 Cs[32 * 64];
    __shared__ float dts[32 * 4];   // [t][dl]
    __shared__ float us[32 * 4];
    int lane = threadIdx.x;
    int n = lane & 15, dl = lane >> 4;
    int d0 = blockIdx.x * 4;
    int b = blockIdx.y;
    int d = d0 + dl;
    float A_dn = -__expf(A_log[d * 16 + n]);
    float Dsk = Dskip[d];
    const u16* pb = p + (size_t)b * 1024 * OPAD;
    const float* dtb = dt + (size_t)b * 1024 * DI;
    const float* ub  = u  + (size_t)b * 1024 * DI;
    float* yb        = y  + (size_t)b * 1024 * DI;

    // staging indices: f = it*64+lane; row t=f/8, 16B-seg s=f%8 (row=128B)
    int srow = lane >> 3;           // t contribution within group of 8 rows
    int sseg = (lane & 7) * 8;      // u16 offset of 16B segment within row

    float h = 0.f;
    for (int t0 = 0; t0 < 1024; t0 += 32) {
        __syncthreads();  // drain prior chunk's LDS reads before overwrite
        #pragma unroll
        for (int it = 0; it < 4; ++it) {
            int t = it * 8 + srow;
            gload16(pb + (size_t)(t0 + t) * OPAD + B0 + d0 * 16 + sseg,
                    (char*)Bs + it * 1024);
            gload16(pb + (size_t)(t0 + t) * OPAD + C0 + d0 * 16 + sseg,
                    (char*)Cs + it * 1024);
        }
        if (lane < 32) {
            gload16(dtb + (size_t)(t0 + lane) * DI + d0, (char*)dts);
            gload16(ub  + (size_t)(t0 + lane) * DI + d0, (char*)us);
        }
        __syncthreads();  // waits vmcnt(0): staging complete
        #pragma unroll
        for (int t = 0; t < 32; ++t) {
            float Bv = bf2f(Bs[t * 64 + dl * 16 + n]);
            float Cv = bf2f(Cs[t * 64 + dl * 16 + n]);
            float dtv = dts[t * 4 + dl];
            float uv  = us[t * 4 + dl];
            float dA = __expf(dtv * A_dn);
            h = fmaf(dA, h, dtv * uv * Bv);
            float part = Cv * h;
            part += __shfl_xor(part, 1);
            part += __shfl_xor(part, 2);
            part += __shfl_xor(part, 4);
            part += __shfl_xor(part, 8);
            if (n == 0) yb[(size_t)(t0 + t) * DI + d] = part + uv * Dsk;
        }
    }
}

// ---------------- gating + RMSNorm + residual -> g (bf16) --------------------
__global__ void __launch_bounds__(256) gate_kernel(const u16* __restrict__ p,
        const float* __restrict__ y, const float* __restrict__ res,
        const float* __restrict__ norm_w, u16* __restrict__ g) {
    int m = blockIdx.x, tid = threadIdx.x;
    const u16* pz = p + (size_t)m * OPAD + Z0;
    const float* yr = y + (size_t)m * DI;
    float gp[6];
    float ss = 0.f, dummy = 0.f;
    #pragma unroll
    for (int i = 0; i < 6; ++i) {
        int d = i * 256 + tid;
        float z = bf2f(pz[d]);
        float gv = yr[d] * z / (1.f + __expf(-z));
        gp[i] = gv;
        ss += gv * gv;
    }
    block_reduce2(ss, dummy);
    float scale = rsqrtf(ss * (1.f / DI) + 1e-6f);
    #pragma unroll
    for (int i = 0; i < 6; ++i) {
        int d = i * 256 + tid;
        float val = gp[i] * scale * norm_w[d] + res[(size_t)m * DI + d];
        g[(size_t)m * DI + d] = f2bf(val);
    }
}

// ---------------- host ----------------
extern "C" void kernel_launch(void* const* d_in, const int* in_sizes, int n_in,
                              void* d_out, int out_size, void* d_ws, size_t ws_size,
                              hipStream_t stream) {
    const float* x       = (const float*)d_in[0];
    const float* ln_w    = (const float*)d_in[1];
    const float* ln_b    = (const float*)d_in[2];
    const float* W_in    = (const float*)d_in[3];
    const float* W_dt    = (const float*)d_in[4];
    const float* conv_w  = (const float*)d_in[5];
    const float* conv_b  = (const float*)d_in[6];
    const float* A_log   = (const float*)d_in[7];
    const float* Dskip   = (const float*)d_in[8];
    const float* dt_bias = (const float*)d_in[9];
    const float* norm_w  = (const float*)d_in[10];
    const float* W_res   = (const float*)d_in[11];
    const float* W_out   = (const float*)d_in[12];
    float* out = (float*)d_out;

    char* wsb = (char*)d_ws;
    u16* Wbf     = (u16*)(wsb + 0);           //  80,412,672  (OPAD*768*2)
    u16* Wresbf  = (u16*)(wsb + 80412672);    //   2,359,296
    u16* Woutbf  = (u16*)(wsb + 82771968);    //   2,359,296
    u16* xnbf    = (u16*)(wsb + 85131264);    //   3,145,728
    u16* xbf     = (u16*)(wsb + 88276992);    //   3,145,728
    u16* pbuf    = (u16*)(wsb + 91422720);    // 214,433,792  (2048*OPAD*2)
    float* ucv   = (float*)(wsb + 305856512); //  12,582,912
    float* dtv   = (float*)(wsb + 318439424); //  12,582,912
    float* ybuf  = (float*)(wsb + 331022336); //  12,582,912
    float* resb  = (float*)(wsb + 343605248); //  12,582,912
    u16* gbuf    = (u16*)(wsb + 356188160);   //   6,291,456  -> total 362,479,616

    // 1) weight converts
    cvt_kernel<<<39264, 256, 0, stream>>>(W_in, Wbf, (long)OTOT * DM, (long)OPAD * DM);
    cvt_kernel<<<1152, 256, 0, stream>>>(W_res, Wresbf, (long)DI * DM, (long)DI * DM);
    cvt_kernel<<<1152, 256, 0, stream>>>(W_out, Woutbf, (long)DM * DI, (long)DM * DI);
    // 2) layernorm
    ln_kernel<<<2048, 256, 0, stream>>>(x, ln_w, ln_b, xnbf, xbf);
    // 3) big GEMM: p = xn @ W_in^T  (bf16 out, ldc = OPAD)
    gemm_bt<1><<<dim3(409, 16), 256, 0, stream>>>(xnbf, Wbf, pbuf, DM, OPAD);
    // 4) res = x @ W_res^T (f32 out)
    gemm_bt<0><<<dim3(12, 16), 256, 0, stream>>>(xbf, Wresbf, resb, DM, DI);
    // 5) conv
    conv_kernel<<<dim3(6, 2048), 256, 0, stream>>>(pbuf, conv_w, conv_b, ucv);
    // 6) dt
    dt_kernel<<<128, 256, 0, stream>>>(pbuf, W_dt, dt_bias, dtv);
    // 7) scan v2: 1-wave blocks, 4d x 16n, LDS chunk staging
    scan_kernel<<<dim3(384, 2), 64, 0, stream>>>(pbuf, dtv, ucv, A_log, Dskip, ybuf);
    // 8) gate + rmsnorm + residual
    gate_kernel<<<2048, 256, 0, stream>>>(pbuf, ybuf, resb, norm_w, gbuf);
    // 9) out = g @ W_out^T (f32 out)
    gemm_bt<0><<<dim3(6, 16), 256, 0, stream>>>(gbuf, Woutbf, out, DI, DM);
}

// Round 3
// 836.903 us; speedup vs baseline: 1.6163x; 1.0728x over previous
//
#include <hip/hip_runtime.h>

// HybridMambaBlock pipeline:
//  1) cvt: W_in/W_res/W_out f32 -> bf16 (W_in padded to OPAD rows, zero fill)
//  2) ln: LayerNorm(x) -> xn(bf16); also x -> bf16 for the residual GEMM
//  3) gemm_bt<bf16 out>: p = xn @ W_in^T   (2048 x 52352, the big one)
//  4) gemm_bt<f32 out>:  res = x @ W_res^T
//  5) conv: depthwise causal conv K=4 on u slice of p -> u_conv (f32)
//  6) dt: dt = clip(softplus(dth @ W_dt^T + bias), 1e-4, 1)
//  7) scan: chunked-LDS selective scan (1 wave/block, 4d x 16n, T_CH=32)
//  8) gate: g = rmsnorm(y*silu(z))*norm_w + res -> bf16
//  9) gemm_bt<f32 out>: out = g @ W_out^T
//
// R2 changes (gemm_bt only):
//  - grid swapped to (x=m, y=n): m-tiles sharing a W-slice are co-resident ->
//    W fetched from HBM once (FETCH 648MB -> ~110MB predicted)
//  - XOR swizzle of 16B segments in LDS (gather-side permute to respect the
//    wave-uniform global_load_lds destination) -> conflict-free ds_read_b128

typedef unsigned short u16;
typedef __bf16 bf16x8 __attribute__((ext_vector_type(8)));
typedef float f32x4 __attribute__((ext_vector_type(4)));

#define OPAD 52352   // 409*128 >= 52272
#define OTOT 52272
#define DI   1536
#define DM   768
#define Z0   0
#define U0   1536
#define DTH0 3072
#define B0   3120
#define C0   27696

__device__ static inline u16 f2bf(float f) {
    unsigned u = __float_as_uint(f);
    u += 0x7fffu + ((u >> 16) & 1u);
    return (u16)(u >> 16);
}
__device__ static inline float bf2f(u16 s) {
    return __uint_as_float(((unsigned)s) << 16);
}

__device__ static inline void gload16(const void* g, void* l) {
    __builtin_amdgcn_global_load_lds(
        (const __attribute__((address_space(1))) unsigned int*)g,
        (__attribute__((address_space(3))) unsigned int*)l, 16, 0, 0);
}

// ---------------- f32 -> bf16 convert (with zero pad to n_tot) ----------------
__global__ void cvt_kernel(const float* __restrict__ src, u16* __restrict__ dst,
                           long n_src, long n_tot) {
    long i4 = ((long)blockIdx.x * 256 + threadIdx.x) * 4;
    if (i4 >= n_tot) return;
    ushort4 o;
    if (i4 < n_src) {  // n_src is a multiple of 4 for all callers
        float4 v = *(const float4*)(src + i4);
        o.x = f2bf(v.x); o.y = f2bf(v.y); o.z = f2bf(v.z); o.w = f2bf(v.w);
    } else {
        o.x = o.y = o.z = o.w = 0;
    }
    *(ushort4*)(dst + i4) = o;
}

// ---------------- block reduce (sum of two values across 256 threads) --------
__device__ static inline void block_reduce2(float& a, float& b) {
    #pragma unroll
    for (int o = 32; o > 0; o >>= 1) {
        a += __shfl_down(a, o);
        b += __shfl_down(b, o);
    }
    __shared__ float sa[4], sb[4];
    int lane = threadIdx.x & 63, w = threadIdx.x >> 6;
    if (lane == 0) { sa[w] = a; sb[w] = b; }
    __syncthreads();
    a = sa[0] + sa[1] + sa[2] + sa[3];
    b = sb[0] + sb[1] + sb[2] + sb[3];
}

// ---------------- LayerNorm -> xn bf16, plus raw x -> bf16 -------------------
__global__ void __launch_bounds__(256) ln_kernel(const float* __restrict__ x,
        const float* __restrict__ w, const float* __restrict__ b,
        u16* __restrict__ xnbf, u16* __restrict__ xbf) {
    int m = blockIdx.x, tid = threadIdx.x;
    const float* xr = x + (size_t)m * DM;
    float v[3];
    v[0] = xr[tid]; v[1] = xr[tid + 256]; v[2] = xr[tid + 512];
    float s = v[0] + v[1] + v[2];
    float ss = v[0]*v[0] + v[1]*v[1] + v[2]*v[2];
    block_reduce2(s, ss);
    float mu = s * (1.f / DM);
    float var = ss * (1.f / DM) - mu * mu;
    float inv = rsqrtf(var + 1e-5f);
    #pragma unroll
    for (int i = 0; i < 3; ++i) {
        int d = tid + i * 256;
        float xn = (v[i] - mu) * inv * w[d] + b[d];
        xnbf[(size_t)m * DM + d] = f2bf(xn);
        xbf[(size_t)m * DM + d] = f2bf(v[i]);
    }
}

// ---------------- bf16 MFMA GEMM: C[M,N] = A[M,K] * B[N,K]^T -----------------
// 128x128 tile, BK=64, 256 threads (4 waves, each 64x64 via 4x4 of 16x16x32).
// Grid: x = m-tile (fastest -> W-slice reuse across co-resident m-tiles),
//       y = n-tile.
// LDS: 8 16B-segments per 128B row, stored at slot (seg ^ (row&7)) via
// gather-side permute; fragment reads address slot ((l4+kk8) ^ (l15&7)) ->
// 8 lanes per 4-bank group (2-way/bank = free).
template <int OUT_BF16>
__global__ void __launch_bounds__(256) gemm_bt(const u16* __restrict__ A,
        const u16* __restrict__ B, void* __restrict__ C, int K, int ldc) {
    __shared__ u16 smem[2 * 128 * 64];
    u16* As = smem;
    u16* Bs = smem + 128 * 64;
    int tid = threadIdx.x;
    int m0 = blockIdx.x * 128, n0 = blockIdx.y * 128;
    int lane = tid & 63, wave = tid >> 6;
    int wm = wave >> 1, wn = wave & 1;
    int l15 = lane & 15, l4 = lane >> 4;
    f32x4 acc[4][4] = {};
    const u16* Ag = A + (size_t)m0 * K;
    const u16* Bg = B + (size_t)n0 * K;
    int crow = tid >> 3;                              // 0..31: row within 32-row group
    int ccol = ((tid & 7) ^ ((tid >> 3) & 7)) * 8;    // swizzled 16B segment
    int ldsoff = (tid & 192) * 16;                    // wave*1024 bytes
    int xr = l15 & 7;                                 // read-side swizzle key

    for (int k0 = 0; k0 < K; k0 += 64) {
        __syncthreads();
        #pragma unroll
        for (int it = 0; it < 4; ++it) {
            gload16(Ag + (size_t)(it * 32 + crow) * K + k0 + ccol,
                    (char*)As + it * 4096 + ldsoff);
            gload16(Bg + (size_t)(it * 32 + crow) * K + k0 + ccol,
                    (char*)Bs + it * 4096 + ldsoff);
        }
        __syncthreads();
        const u16* Arow = As + (wm * 64 + l15) * 64;
        const u16* Brow = Bs + (wn * 64 + l15) * 64;
        #pragma unroll
        for (int kk8 = 0; kk8 < 8; kk8 += 4) {
            int sw = ((l4 + kk8) ^ xr) * 8;
            bf16x8 af[4], bfr[4];
            #pragma unroll
            for (int i = 0; i < 4; ++i) af[i] = *(const bf16x8*)(Arow + i * 16 * 64 + sw);
            #pragma unroll
            for (int j = 0; j < 4; ++j) bfr[j] = *(const bf16x8*)(Brow + j * 16 * 64 + sw);
            #pragma unroll
            for (int i = 0; i < 4; ++i)
                #pragma unroll
                for (int j = 0; j < 4; ++j)
                    acc[i][j] = __builtin_amdgcn_mfma_f32_16x16x32_bf16(
                        af[i], bfr[j], acc[i][j], 0, 0, 0);
        }
    }
    #pragma unroll
    for (int i = 0; i < 4; ++i) {
        int row = m0 + wm * 64 + i * 16 + l4 * 4;
        #pragma unroll
        for (int j = 0; j < 4; ++j) {
            int col = n0 + wn * 64 + j * 16 + l15;
            #pragma unroll
            for (int r = 0; r < 4; ++r) {
                size_t off = (size_t)(row + r) * ldc + col;
                if (OUT_BF16) ((u16*)C)[off] = f2bf(acc[i][j][r]);
                else          ((float*)C)[off] = acc[i][j][r];
            }
        }
    }
}

// ---------------- depthwise causal conv (K=4) --------------------------------
__global__ void __launch_bounds__(256) conv_kernel(const u16* __restrict__ p,
        const float* __restrict__ cw, const float* __restrict__ cb,
        float* __restrict__ u) {
    int d = blockIdx.x * 256 + threadIdx.x;  // 0..1535
    int m = blockIdx.y;                      // 0..2047
    int l = m & 1023;
    int bm = m - l;                          // b*1024
    float acc = cb[d];
    #pragma unroll
    for (int j = 0; j < 4; ++j) {
        int ls = l - 3 + j;
        if (ls >= 0)
            acc += cw[d * 4 + j] * bf2f(p[(size_t)(bm + ls) * OPAD + U0 + d]);
    }
    u[(size_t)m * DI + d] = acc;
}

// ---------------- dt = clip(softplus(dth @ W_dt^T + bias)) -------------------
__global__ void __launch_bounds__(256) dt_kernel(const u16* __restrict__ p,
        const float* __restrict__ Wdt, const float* __restrict__ dt_bias,
        float* __restrict__ dt) {
    int m0 = blockIdx.x * 16, tid = threadIdx.x;
    __shared__ float dth_s[16 * 48];
    for (int i = tid; i < 16 * 48; i += 256)
        dth_s[i] = bf2f(p[(size_t)(m0 + i / 48) * OPAD + DTH0 + (i % 48)]);
    __syncthreads();
    #pragma unroll
    for (int ii = 0; ii < 6; ++ii) {
        int d = ii * 256 + tid;
        float base = dt_bias[d];
        float acc[16];
        #pragma unroll
        for (int mm = 0; mm < 16; ++mm) acc[mm] = base;
        for (int r = 0; r < 48; ++r) {
            float wv = Wdt[d * 48 + r];
            #pragma unroll
            for (int mm = 0; mm < 16; ++mm)
                acc[mm] = fmaf(wv, dth_s[mm * 48 + r], acc[mm]);
        }
        #pragma unroll
        for (int mm = 0; mm < 16; ++mm) {
            float xv = acc[mm];
            float sp = xv > 20.f ? xv : log1pf(__expf(xv));
            sp = fminf(fmaxf(sp, 1e-4f), 1.0f);
            dt[(size_t)(m0 + mm) * DI + d] = sp;
        }
    }
}

// ---------------- selective scan v2: chunked LDS staging ---------------------
// 1 wave per block; block owns 4 d-channels (all 16 n each). T_CH=32 timesteps
// staged per chunk: B (4KB), C (4KB) via 8x16B fully-used segments per row,
// dt/u (512B each, half-wave masked loads). Inner loop reads LDS (conflict-
// free: 2 lanes/dword broadcast), h-recurrence in a register, 4-shfl n-reduce.
__global__ void __launch_bounds__(64) scan_kernel(const u16* __restrict__ p,
        const float* __restrict__ dt, const float* __restrict__ u,
        const float* __restrict__ A_log, const float* __restrict__ Dskip,
        float* __restrict__ y) {
    __shared__ u16 Bs[32 * 64];     // [t][d*16+n]
    __shared__ u16 Cs[32 * 64];
    __shared__ float dts[32 * 4];   // [t][dl]
    __shared__ float us[32 * 4];
    int lane = threadIdx.x;
    int n = lane & 15, dl = lane >> 4;
    int d0 = blockIdx.x * 4;
    int b = blockIdx.y;
    int d = d0 + dl;
    float A_dn = -__expf(A_log[d * 16 + n]);
    float Dsk = Dskip[d];
    const u16* pb = p + (size_t)b * 1024 * OPAD;
    const float* dtb = dt + (size_t)b * 1024 * DI;
    const float* ub  = u  + (size_t)b * 1024 * DI;
    float* yb        = y  + (size_t)b * 1024 * DI;

    // staging indices: f = it*64+lane; row t=f/8, 16B-seg s=f%8 (row=128B)
    int srow = lane >> 3;           // t contribution within group of 8 rows
    int sseg = (lane & 7) * 8;      // u16 offset of 16B segment within row

    float h = 0.f;
    for (int t0 = 0; t0 < 1024; t0 += 32) {
        __syncthreads();  // drain prior chunk's LDS reads before overwrite
        #pragma unroll
        for (int it = 0; it < 4; ++it) {
            int t = it * 8 + srow;
            gload16(pb + (size_t)(t0 + t) * OPAD + B0 + d0 * 16 + sseg,
                    (char*)Bs + it * 1024);
            gload16(pb + (size_t)(t0 + t) * OPAD + C0 + d0 * 16 + sseg,
                    (char*)Cs + it * 1024);
        }
        if (lane < 32) {
            gload16(dtb + (size_t)(t0 + lane) * DI + d0, (char*)dts);
            gload16(ub  + (size_t)(t0 + lane) * DI + d0, (char*)us);
        }
        __syncthreads();  // waits vmcnt(0): staging complete
        #pragma unroll
        for (int t = 0; t < 32; ++t) {
            float Bv = bf2f(Bs[t * 64 + dl * 16 + n]);
            float Cv = bf2f(Cs[t * 64 + dl * 16 + n]);
            float dtv = dts[t * 4 + dl];
            float uv  = us[t * 4 + dl];
            float dA = __expf(dtv * A_dn);
            h = fmaf(dA, h, dtv * uv * Bv);
            float part = Cv * h;
            part += __shfl_xor(part, 1);
            part += __shfl_xor(part, 2);
            part += __shfl_xor(part, 4);
            part += __shfl_xor(part, 8);
            if (n == 0) yb[(size_t)(t0 + t) * DI + d] = part + uv * Dsk;
        }
    }
}

// ---------------- gating + RMSNorm + residual -> g (bf16) --------------------
__global__ void __launch_bounds__(256) gate_kernel(const u16* __restrict__ p,
        const float* __restrict__ y, const float* __restrict__ res,
        const float* __restrict__ norm_w, u16* __restrict__ g) {
    int m = blockIdx.x, tid = threadIdx.x;
    const u16* pz = p + (size_t)m * OPAD + Z0;
    const float* yr = y + (size_t)m * DI;
    float gp[6];
    float ss = 0.f, dummy = 0.f;
    #pragma unroll
    for (int i = 0; i < 6; ++i) {
        int d = i * 256 + tid;
        float z = bf2f(pz[d]);
        float gv = yr[d] * z / (1.f + __expf(-z));
        gp[i] = gv;
        ss += gv * gv;
    }
    block_reduce2(ss, dummy);
    float scale = rsqrtf(ss * (1.f / DI) + 1e-6f);
    #pragma unroll
    for (int i = 0; i < 6; ++i) {
        int d = i * 256 + tid;
        float val = gp[i] * scale * norm_w[d] + res[(size_t)m * DI + d];
        g[(size_t)m * DI + d] = f2bf(val);
    }
}

// ---------------- host ----------------
extern "C" void kernel_launch(void* const* d_in, const int* in_sizes, int n_in,
                              void* d_out, int out_size, void* d_ws, size_t ws_size,
                              hipStream_t stream) {
    const float* x       = (const float*)d_in[0];
    const float* ln_w    = (const float*)d_in[1];
    const float* ln_b    = (const float*)d_in[2];
    const float* W_in    = (const float*)d_in[3];
    const float* W_dt    = (const float*)d_in[4];
    const float* conv_w  = (const float*)d_in[5];
    const float* conv_b  = (const float*)d_in[6];
    const float* A_log   = (const float*)d_in[7];
    const float* Dskip   = (const float*)d_in[8];
    const float* dt_bias = (const float*)d_in[9];
    const float* norm_w  = (const float*)d_in[10];
    const float* W_res   = (const float*)d_in[11];
    const float* W_out   = (const float*)d_in[12];
    float* out = (float*)d_out;

    char* wsb = (char*)d_ws;
    u16* Wbf     = (u16*)(wsb + 0);           //  80,412,672  (OPAD*768*2)
    u16* Wresbf  = (u16*)(wsb + 80412672);    //   2,359,296
    u16* Woutbf  = (u16*)(wsb + 82771968);    //   2,359,296
    u16* xnbf    = (u16*)(wsb + 85131264);    //   3,145,728
    u16* xbf     = (u16*)(wsb + 88276992);    //   3,145,728
    u16* pbuf    = (u16*)(wsb + 91422720);    // 214,433,792  (2048*OPAD*2)
    float* ucv   = (float*)(wsb + 305856512); //  12,582,912
    float* dtv   = (float*)(wsb + 318439424); //  12,582,912
    float* ybuf  = (float*)(wsb + 331022336); //  12,582,912
    float* resb  = (float*)(wsb + 343605248); //  12,582,912
    u16* gbuf    = (u16*)(wsb + 356188160);   //   6,291,456  -> total 362,479,616

    // 1) weight converts
    cvt_kernel<<<39264, 256, 0, stream>>>(W_in, Wbf, (long)OTOT * DM, (long)OPAD * DM);
    cvt_kernel<<<1152, 256, 0, stream>>>(W_res, Wresbf, (long)DI * DM, (long)DI * DM);
    cvt_kernel<<<1152, 256, 0, stream>>>(W_out, Woutbf, (long)DM * DI, (long)DM * DI);
    // 2) layernorm
    ln_kernel<<<2048, 256, 0, stream>>>(x, ln_w, ln_b, xnbf, xbf);
    // 3) big GEMM: p = xn @ W_in^T  (bf16 out, ldc = OPAD); grid x=m, y=n
    gemm_bt<1><<<dim3(16, 409), 256, 0, stream>>>(xnbf, Wbf, pbuf, DM, OPAD);
    // 4) res = x @ W_res^T (f32 out)
    gemm_bt<0><<<dim3(16, 12), 256, 0, stream>>>(xbf, Wresbf, resb, DM, DI);
    // 5) conv
    conv_kernel<<<dim3(6, 2048), 256, 0, stream>>>(pbuf, conv_w, conv_b, ucv);
    // 6) dt
    dt_kernel<<<128, 256, 0, stream>>>(pbuf, W_dt, dt_bias, dtv);
    // 7) scan v2: 1-wave blocks, 4d x 16n, LDS chunk staging
    scan_kernel<<<dim3(384, 2), 64, 0, stream>>>(pbuf, dtv, ucv, A_log, Dskip, ybuf);
    // 8) gate + rmsnorm + residual
    gate_kernel<<<2048, 256, 0, stream>>>(pbuf, ybuf, resb, norm_w, gbuf);
    // 9) out = g @ W_out^T (f32 out)
    gemm_bt<0><<<dim3(16, 6), 256, 0, stream>>>(gbuf, Woutbf, out, DI, DM);
}